// Round 2
// baseline (258.560 us; speedup 1.0000x reference)
//
#include <hip/hip_runtime.h>
#include <hip/hip_fp16.h>
#include <stdint.h>

typedef int v4i __attribute__((ext_vector_type(4)));

#define GLOAD_LDS16(g, l) __builtin_amdgcn_global_load_lds(                  \
    (const __attribute__((address_space(1))) void*)(g),                      \
    (__attribute__((address_space(3))) void*)(l), 16, 0, 0)

// workspace layout (bytes)
#define XQ_OFF    0u
#define XS_OFF    33554432u              // M*K int8
#define W8_OFF    33570816u              // + M*2 fp16 scales
#define FLAGS_OFF 50348032u              // + N*K int8

// ---------------------------------------------------------------------------
// Probe: classify input delivery. flags[0]=1 if x is fp32(widened fp16);
// flags[1]=1 if w is int32(widened int8).
// ---------------------------------------------------------------------------
__global__ __launch_bounds__(256) void probe_dtypes(
    const uint32_t* __restrict__ xw, const int* __restrict__ ww, int* flags)
{
  __shared__ int cnt[2];
  if (threadIdx.x == 0) { cnt[0] = 0; cnt[1] = 0; }
  __syncthreads();
  int cx = 0, cw = 0;
  for (int i = threadIdx.x; i < 1024; i += 256) {
    cx += ((xw[i] & 0x1FFFu) == 0u) ? 1 : 0;   // f32-from-fp16: low 13 bits zero
    int v = ww[i];
    cw += (v >= -128 && v <= 127) ? 1 : 0;     // int32-from-int8: in-range words
  }
  atomicAdd(&cnt[0], cx);
  atomicAdd(&cnt[1], cw);
  __syncthreads();
  if (threadIdx.x == 0) {
    flags[0] = (cnt[0] >= 1000) ? 1 : 0;
    flags[1] = (cnt[1] >= 1000) ? 1 : 0;
  }
}

// ---------------------------------------------------------------------------
// Repack w into contiguous int8 [N*K] in workspace (either narrowing int32 or
// straight copy of already-int8 bytes).
// ---------------------------------------------------------------------------
__global__ __launch_bounds__(256) void repack_w(
    const void* __restrict__ win, int8_t* __restrict__ w8,
    int total, const int* __restrict__ flags)
{
  const bool as32 = flags[1] != 0;
  const int tid  = blockIdx.x * 256 + threadIdx.x;
  const int nthr = gridDim.x * 256;
  if (as32) {
    const int4* w4 = (const int4*)win;
    uint32_t* dst = (uint32_t*)w8;
    const int n4 = total >> 2;
    for (int i = tid; i < n4; i += nthr) {
      int4 v = w4[i];
      dst[i] = (uint32_t)(v.x & 255) | ((uint32_t)(v.y & 255) << 8) |
               ((uint32_t)(v.z & 255) << 16) | ((uint32_t)(v.w & 255) << 24);
    }
  } else {
    const uint4* src = (const uint4*)win;
    uint4* dst = (uint4*)w8;
    const int n16 = total >> 4;
    for (int i = tid; i < n16; i += nthr) dst[i] = src[i];
  }
}

// ---------------------------------------------------------------------------
// Per-token dynamic symmetric int8 quantization. One block per row of x[M,K].
// scale = max|x|/127 (fp32); q = clip(rint(x/scale),-128,127); xs = half(scale)
// ---------------------------------------------------------------------------
__global__ __launch_bounds__(256) void quant_rows(
    const void* __restrict__ xin, int8_t* __restrict__ xq,
    __half* __restrict__ xs, int K, const int* __restrict__ flags)
{
  const bool xf32 = flags[0] != 0;
  const int row  = blockIdx.x;
  const int tid  = threadIdx.x;
  const int lane = tid & 63;
  const int w    = tid >> 6;
  const size_t base = (size_t)row * (size_t)K;

  float mx = 0.0f;
  if (xf32) {
    const float* x = (const float*)xin + base;
    for (int k = tid * 4; k < K; k += 256 * 4) {
      float4 v = *(const float4*)(x + k);
      mx = fmaxf(mx, fmaxf(fmaxf(fabsf(v.x), fabsf(v.y)),
                           fmaxf(fabsf(v.z), fabsf(v.w))));
    }
  } else {
    const __half* x = (const __half*)xin + base;
    for (int k = tid * 8; k < K; k += 256 * 8) {
      uint4 u = *(const uint4*)(x + k);
      const __half* hp = (const __half*)&u;
      #pragma unroll
      for (int j = 0; j < 8; ++j)
        mx = fmaxf(mx, fabsf(__half2float(hp[j])));
    }
  }
  #pragma unroll
  for (int off = 32; off > 0; off >>= 1)
    mx = fmaxf(mx, __shfl_xor(mx, off, 64));

  __shared__ float wmax[4];
  if (lane == 0) wmax[w] = mx;
  __syncthreads();
  const float m4    = fmaxf(fmaxf(wmax[0], wmax[1]), fmaxf(wmax[2], wmax[3]));
  const float scale = m4 / 127.0f;
  if (tid == 0) xs[row] = __float2half(scale);

  if (xf32) {
    const float* x = (const float*)xin + base;
    for (int k = tid * 8; k < K; k += 256 * 8) {
      float4 a = *(const float4*)(x + k);
      float4 b = *(const float4*)(x + k + 4);
      float v[8] = {a.x, a.y, a.z, a.w, b.x, b.y, b.z, b.w};
      uint32_t p0 = 0, p1 = 0;
      #pragma unroll
      for (int j = 0; j < 4; ++j) {
        float r = fminf(127.0f, fmaxf(-128.0f, rintf(v[j] / scale)));
        p0 |= ((uint32_t)((int)r & 255)) << (8 * j);
      }
      #pragma unroll
      for (int j = 0; j < 4; ++j) {
        float r = fminf(127.0f, fmaxf(-128.0f, rintf(v[4 + j] / scale)));
        p1 |= ((uint32_t)((int)r & 255)) << (8 * j);
      }
      uint2 st; st.x = p0; st.y = p1;
      *(uint2*)(xq + base + k) = st;
    }
  } else {
    const __half* x = (const __half*)xin + base;
    for (int k = tid * 8; k < K; k += 256 * 8) {
      uint4 u = *(const uint4*)(x + k);
      const __half* hp = (const __half*)&u;
      uint32_t p0 = 0, p1 = 0;
      #pragma unroll
      for (int j = 0; j < 4; ++j) {
        float r = fminf(127.0f, fmaxf(-128.0f, rintf(__half2float(hp[j]) / scale)));
        p0 |= ((uint32_t)((int)r & 255)) << (8 * j);
      }
      #pragma unroll
      for (int j = 0; j < 4; ++j) {
        float r = fminf(127.0f, fmaxf(-128.0f, rintf(__half2float(hp[4 + j]) / scale)));
        p1 |= ((uint32_t)((int)r & 255)) << (8 * j);
      }
      uint2 st; st.x = p0; st.y = p1;
      *(uint2*)(xq + base + k) = st;
    }
  }
}

// ---------------------------------------------------------------------------
// int8 GEMM C[m,n] = sum_k xq[m,k]*w8[n,k], 128x128 tile, BK=64, 4 waves 2x2,
// mfma_i32_16x16x64_i8, double-buffered LDS via global_load_lds(16B) with
// chunk-XOR swizzle (pre-swizzled global source + swizzled ds_read).
// ---------------------------------------------------------------------------
__global__ __launch_bounds__(256) void gemm_w8a8(
    const int8_t* __restrict__ xq, const int8_t* __restrict__ wq,
    const __half* __restrict__ xs, const float* __restrict__ wscale,
    const float* __restrict__ mos, float* __restrict__ out,
    int M, int N, int K)
{
  __shared__ int8_t sA[2][128 * 64];
  __shared__ int8_t sB[2][128 * 64];

  const int tid  = threadIdx.x;
  const int lane = tid & 63;
  const int w    = tid >> 6;
  const int wr   = w >> 1;
  const int wc   = w & 1;
  const int lr   = lane & 15;
  const int lk   = lane >> 4;

  const int bn = blockIdx.x * 128;
  const int bm = blockIdx.y * 128;

  v4i acc[4][4];
  #pragma unroll
  for (int i = 0; i < 4; ++i)
    #pragma unroll
    for (int j = 0; j < 4; ++j) {
      v4i z = {0, 0, 0, 0};
      acc[i][j] = z;
    }

  auto stage = [&](int buf, int kt) {
    const int k0 = kt * 64;
    #pragma unroll
    for (int i = 0; i < 2; ++i) {
      const int linear = i * 256 + tid;
      const int r  = linear >> 2;
      const int c  = linear & 3;
      const int sc = c ^ (r & 3);
      const int8_t* ga = xq + (size_t)(bm + r) * K + k0 + sc * 16;
      const int8_t* gb = wq + (size_t)(bn + r) * K + k0 + sc * 16;
      const int ldsoff = (i * 256 + w * 64) * 16;
      GLOAD_LDS16(ga, &sA[buf][ldsoff]);
      GLOAD_LDS16(gb, &sB[buf][ldsoff]);
    }
  };

  const int nt = K >> 6;
  stage(0, 0);
  __syncthreads();

  const int a_off = (wr * 64 + lr) * 64 + ((lk ^ (lr & 3)) << 4);
  const int b_off = (wc * 64 + lr) * 64 + ((lk ^ (lr & 3)) << 4);

  int cur = 0;
  for (int kt = 0; kt < nt; ++kt) {
    if (kt + 1 < nt) stage(cur ^ 1, kt + 1);

    v4i af[4], bf[4];
    #pragma unroll
    for (int mi = 0; mi < 4; ++mi)
      af[mi] = *(const v4i*)(&sA[cur][a_off + mi * 1024]);
    #pragma unroll
    for (int ni = 0; ni < 4; ++ni)
      bf[ni] = *(const v4i*)(&sB[cur][b_off + ni * 1024]);

    #pragma unroll
    for (int mi = 0; mi < 4; ++mi)
      #pragma unroll
      for (int ni = 0; ni < 4; ++ni)
        acc[mi][ni] = __builtin_amdgcn_mfma_i32_16x16x64_i8(
            af[mi], bf[ni], acc[mi][ni], 0, 0, 0);

    __syncthreads();
    cur ^= 1;
  }

  const float s_out = mos[0];
  #pragma unroll
  for (int ni = 0; ni < 4; ++ni) {
    const int n_g = bn + wc * 64 + ni * 16 + lr;
    const float wsc = wscale[n_g];
    #pragma unroll
    for (int mi = 0; mi < 4; ++mi) {
      #pragma unroll
      for (int j = 0; j < 4; ++j) {
        const int m_g = bm + wr * 64 + mi * 16 + lk * 4 + j;
        const float y = __half2float(__float2half((float)acc[mi][ni][j] * s_out));
        out[(size_t)m_g * N + n_g] = (y * wsc) * __half2float(xs[m_g]);
      }
    }
  }
}

// ---------------------------------------------------------------------------
extern "C" void kernel_launch(void* const* d_in, const int* in_sizes, int n_in,
                              void* d_out, int out_size, void* d_ws, size_t ws_size,
                              hipStream_t stream) {
  const void*  x      = d_in[0];
  const void*  win    = d_in[1];
  const float* wscale = (const float*)d_in[2];
  const float* mos    = (const float*)d_in[3];
  float*       out    = (float*)d_out;

  const int N = in_sizes[2];            // 4096
  const int K = in_sizes[1] / N;        // 4096
  const int M = in_sizes[0] / K;        // 8192

  int8_t* xq    = (int8_t*)d_ws + XQ_OFF;
  __half* xs    = (__half*)((char*)d_ws + XS_OFF);
  int8_t* w8    = (int8_t*)d_ws + W8_OFF;
  int*    flags = (int*)((char*)d_ws + FLAGS_OFF);

  probe_dtypes<<<1, 256, 0, stream>>>((const uint32_t*)x, (const int*)win, flags);
  repack_w<<<2048, 256, 0, stream>>>(win, w8, N * K, flags);
  quant_rows<<<M, 256, 0, stream>>>(x, xq, xs, K, flags);

  dim3 grid(N / 128, M / 128);
  gemm_w8a8<<<grid, 256, 0, stream>>>(xq, w8, xs, wscale, mos, out, M, N, K);
}

// Round 3
// 215.872 us; speedup vs baseline: 1.1977x; 1.1977x over previous
//
#include <hip/hip_runtime.h>
#include <hip/hip_fp16.h>
#include <stdint.h>

typedef int v4i __attribute__((ext_vector_type(4)));

#define GLOAD_LDS16(g, l) __builtin_amdgcn_global_load_lds(                  \
    (const __attribute__((address_space(1))) void*)(g),                      \
    (__attribute__((address_space(3))) void*)(l), 16, 0, 0)

// workspace layout (bytes)
#define XQ_OFF 0u
#define XS_OFF 33554432u              // M*K int8
#define W8_OFF 33570816u              // + M*2 fp16 scales

// ---------------------------------------------------------------------------
// Self-classification of input delivery (deterministic, per-block, no probe
// kernel): x widened fp16->f32 has low 13 mantissa bits zero in every word;
// w widened int8->int32 has every word in [-128,127].
// ---------------------------------------------------------------------------
__device__ inline bool x_is_f32(const void* xin) {
  const uint32_t* xw = (const uint32_t*)xin;
  bool ok = true;
  #pragma unroll
  for (int i = 0; i < 16; ++i) ok &= ((xw[i] & 0x1FFFu) == 0u);
  return ok;
}
__device__ inline bool w_is_i32(const void* win) {
  const int* wi = (const int*)win;
  bool ok = true;
  #pragma unroll
  for (int i = 0; i < 16; ++i) ok &= (wi[i] >= -128 && wi[i] <= 127);
  return ok;
}

// ---------------------------------------------------------------------------
// Repack w into contiguous int8 [N*K] (narrow int32 or straight copy).
// ---------------------------------------------------------------------------
__global__ __launch_bounds__(256) void repack_w(
    const void* __restrict__ win, int8_t* __restrict__ w8, int total)
{
  const bool as32 = w_is_i32(win);
  const int tid  = blockIdx.x * 256 + threadIdx.x;
  const int nthr = gridDim.x * 256;
  if (as32) {
    const int4* w4 = (const int4*)win;
    uint32_t* dst = (uint32_t*)w8;
    const int n4 = total >> 2;
    for (int i = tid; i < n4; i += nthr) {
      int4 v = w4[i];
      dst[i] = (uint32_t)(v.x & 255) | ((uint32_t)(v.y & 255) << 8) |
               ((uint32_t)(v.z & 255) << 16) | ((uint32_t)(v.w & 255) << 24);
    }
  } else {
    const uint4* src = (const uint4*)win;
    uint4* dst = (uint4*)w8;
    const int n16 = total >> 4;
    for (int i = tid; i < n16; i += nthr) dst[i] = src[i];
  }
}

// ---------------------------------------------------------------------------
// Per-token dynamic symmetric int8 quantization, one block per row.
// Fast path (f32 input, K==4096): row cached in registers, single HBM pass.
// scale = max|x|/127 (fp32); q = clip(rint(x/scale),-128,127); xs = half(scale)
// ---------------------------------------------------------------------------
__global__ __launch_bounds__(256) void quant_rows(
    const void* __restrict__ xin, int8_t* __restrict__ xq,
    __half* __restrict__ xs, int K)
{
  const bool xf32 = x_is_f32(xin);
  const int row  = blockIdx.x;
  const int tid  = threadIdx.x;
  const int lane = tid & 63;
  const int wv   = tid >> 6;
  const size_t base = (size_t)row * (size_t)K;
  __shared__ float wmax[4];

  if (xf32 && K == 4096) {
    const float4* x4 = (const float4*)((const float*)xin + base);
    float4 v[4];
    #pragma unroll
    for (int i = 0; i < 4; ++i) v[i] = x4[i * 256 + tid];
    float mx = 0.0f;
    #pragma unroll
    for (int i = 0; i < 4; ++i)
      mx = fmaxf(mx, fmaxf(fmaxf(fabsf(v[i].x), fabsf(v[i].y)),
                           fmaxf(fabsf(v[i].z), fabsf(v[i].w))));
    #pragma unroll
    for (int off = 32; off; off >>= 1) mx = fmaxf(mx, __shfl_xor(mx, off, 64));
    if (lane == 0) wmax[wv] = mx;
    __syncthreads();
    const float scale =
        fmaxf(fmaxf(wmax[0], wmax[1]), fmaxf(wmax[2], wmax[3])) / 127.0f;
    if (tid == 0) xs[row] = __float2half(scale);
    uint32_t* q = (uint32_t*)(xq + base);
    #pragma unroll
    for (int i = 0; i < 4; ++i) {
      float f[4] = {v[i].x, v[i].y, v[i].z, v[i].w};
      uint32_t p = 0;
      #pragma unroll
      for (int j = 0; j < 4; ++j) {
        float r = fminf(127.0f, fmaxf(-128.0f, rintf(f[j] / scale)));
        p |= ((uint32_t)((int)r & 255)) << (8 * j);
      }
      q[i * 256 + tid] = p;
    }
    return;
  }

  // generic two-pass fallback
  float mx = 0.0f;
  if (xf32) {
    const float* x = (const float*)xin + base;
    for (int k = tid * 4; k < K; k += 256 * 4) {
      float4 v = *(const float4*)(x + k);
      mx = fmaxf(mx, fmaxf(fmaxf(fabsf(v.x), fabsf(v.y)),
                           fmaxf(fabsf(v.z), fabsf(v.w))));
    }
  } else {
    const __half* x = (const __half*)xin + base;
    for (int k = tid * 8; k < K; k += 256 * 8) {
      uint4 u = *(const uint4*)(x + k);
      const __half* hp = (const __half*)&u;
      #pragma unroll
      for (int j = 0; j < 8; ++j) mx = fmaxf(mx, fabsf(__half2float(hp[j])));
    }
  }
  #pragma unroll
  for (int off = 32; off; off >>= 1) mx = fmaxf(mx, __shfl_xor(mx, off, 64));
  if (lane == 0) wmax[wv] = mx;
  __syncthreads();
  const float scale =
      fmaxf(fmaxf(wmax[0], wmax[1]), fmaxf(wmax[2], wmax[3])) / 127.0f;
  if (tid == 0) xs[row] = __float2half(scale);

  for (int k = tid * 8; k < K; k += 256 * 8) {
    float f[8];
    if (xf32) {
      const float* x = (const float*)xin + base;
      float4 a = *(const float4*)(x + k);
      float4 b = *(const float4*)(x + k + 4);
      f[0]=a.x; f[1]=a.y; f[2]=a.z; f[3]=a.w; f[4]=b.x; f[5]=b.y; f[6]=b.z; f[7]=b.w;
    } else {
      const __half* x = (const __half*)xin + base;
      uint4 u = *(const uint4*)(x + k);
      const __half* hp = (const __half*)&u;
      #pragma unroll
      for (int j = 0; j < 8; ++j) f[j] = __half2float(hp[j]);
    }
    uint32_t p0 = 0, p1 = 0;
    #pragma unroll
    for (int j = 0; j < 4; ++j) {
      float r = fminf(127.0f, fmaxf(-128.0f, rintf(f[j] / scale)));
      p0 |= ((uint32_t)((int)r & 255)) << (8 * j);
    }
    #pragma unroll
    for (int j = 0; j < 4; ++j) {
      float r = fminf(127.0f, fmaxf(-128.0f, rintf(f[4 + j] / scale)));
      p1 |= ((uint32_t)((int)r & 255)) << (8 * j);
    }
    uint2 st; st.x = p0; st.y = p1;
    *(uint2*)(xq + base + k) = st;
  }
}

// ---------------------------------------------------------------------------
// int8 GEMM, 256x256 tile, BK=64, 8 waves (2Mx4N), quad-buffered LDS (128KiB),
// counted vmcnt(8) deep pipeline (3 K-tiles in flight), raw s_barrier (1/iter),
// 2-way-free LDS swizzle g(r)=(r>>1)&3, setprio around MFMA clusters.
// Requires K % 64 == 0, K/64 >= 4, M,N % 256 == 0.
// ---------------------------------------------------------------------------
__global__ __launch_bounds__(512, 2) void gemm_w8a8(
    const int8_t* __restrict__ xq, const int8_t* __restrict__ wq,
    const __half* __restrict__ xs, const float* __restrict__ wscale,
    const float* __restrict__ mos, float* __restrict__ out,
    int M, int N, int K)
{
  __shared__ int8_t sA[4][256 * 64];   // 64 KiB
  __shared__ int8_t sB[4][256 * 64];   // 64 KiB

  const int tid  = threadIdx.x;
  const int lane = tid & 63;
  const int w    = tid >> 6;
  const int wr   = w >> 2;        // 0..1 -> 128 rows of C
  const int wc   = w & 3;         // 0..3 -> 64 cols of C
  const int lr   = lane & 15;
  const int lk   = lane >> 4;

  // XCD-aware swizzle (bijective: gridDim.x % 8 == 0 for our shapes)
  int L = blockIdx.x;
  const int nwg = gridDim.x;
  if ((nwg & 7) == 0) L = (L & 7) * (nwg >> 3) + (L >> 3);
  const int ntn = N >> 8;
  const int bn = (L % ntn) << 8;
  const int bm = (L / ntn) << 8;

  v4i acc[8][4];
  #pragma unroll
  for (int i = 0; i < 8; ++i)
    #pragma unroll
    for (int j = 0; j < 4; ++j) {
      v4i z = {0, 0, 0, 0};
      acc[i][j] = z;
    }

  // stage 256x64B tile; LDS pos (r,p) holds global chunk p ^ ((r>>1)&3)
  auto stageA = [&](int kt, int buf) {
    const int k0 = kt << 6;
    #pragma unroll
    for (int i = 0; i < 2; ++i) {
      const int li = i * 512 + tid;
      const int r  = li >> 2;
      const int p  = li & 3;
      const int sc = p ^ ((r >> 1) & 3);
      GLOAD_LDS16(xq + (size_t)(bm + r) * K + k0 + (sc << 4),
                  &sA[buf][(i * 512 + (w << 6)) << 4]);
    }
  };
  auto stageB = [&](int kt, int buf) {
    const int k0 = kt << 6;
    #pragma unroll
    for (int i = 0; i < 2; ++i) {
      const int li = i * 512 + tid;
      const int r  = li >> 2;
      const int p  = li & 3;
      const int sc = p ^ ((r >> 1) & 3);
      GLOAD_LDS16(wq + (size_t)(bn + r) * K + k0 + (sc << 4),
                  &sB[buf][(i * 512 + (w << 6)) << 4]);
    }
  };

  // swizzled ds_read byte offsets; invariant under row += 16 steps
  const int rowA0 = (wr << 7) + lr;
  const int aoff  = rowA0 * 64 + ((lk ^ ((rowA0 >> 1) & 3)) << 4);
  const int rowB0 = (wc << 6) + lr;
  const int boff  = rowB0 * 64 + ((lk ^ ((rowB0 >> 1) & 3)) << 4);

  auto tile_body = [&](int buf, int kstage, bool do_stage) {
    const int8_t* Ab = sA[buf];
    const int8_t* Bb = sB[buf];
    const int sbuf = (buf + 3) & 3;
    if (do_stage) stageA(kstage, sbuf);
    v4i bf[4], af[4];
    #pragma unroll
    for (int ni = 0; ni < 4; ++ni) bf[ni] = *(const v4i*)(Bb + boff + ni * 1024);
    #pragma unroll
    for (int mi = 0; mi < 4; ++mi) af[mi] = *(const v4i*)(Ab + aoff + mi * 1024);
    __builtin_amdgcn_s_setprio(1);
    #pragma unroll
    for (int mi = 0; mi < 4; ++mi)
      #pragma unroll
      for (int ni = 0; ni < 4; ++ni)
        acc[mi][ni] = __builtin_amdgcn_mfma_i32_16x16x64_i8(
            af[mi], bf[ni], acc[mi][ni], 0, 0, 0);
    __builtin_amdgcn_s_setprio(0);
    if (do_stage) stageB(kstage, sbuf);
    #pragma unroll
    for (int mi = 0; mi < 4; ++mi)
      af[mi] = *(const v4i*)(Ab + aoff + 4096 + mi * 1024);
    __builtin_amdgcn_s_setprio(1);
    #pragma unroll
    for (int mi = 0; mi < 4; ++mi)
      #pragma unroll
      for (int ni = 0; ni < 4; ++ni)
        acc[mi + 4][ni] = __builtin_amdgcn_mfma_i32_16x16x64_i8(
            af[mi], bf[ni], acc[mi + 4][ni], 0, 0, 0);
    __builtin_amdgcn_s_setprio(0);
  };

  const int nt = K >> 6;

  // prologue: 3 tiles in flight; wait for tile 0 only (8 newest stay out)
  stageA(0, 0); stageB(0, 0);
  stageA(1, 1); stageB(1, 1);
  stageA(2, 2); stageB(2, 2);
  asm volatile("s_waitcnt vmcnt(8)" ::: "memory");
  __builtin_amdgcn_s_barrier();

  #pragma unroll 1
  for (int t = 0; t < nt - 3; ++t) {
    tile_body(t & 3, t + 3, true);
    // tile t+1 landed; tiles t+2, t+3 (8 loads) stay in flight
    asm volatile("s_waitcnt vmcnt(8) lgkmcnt(0)" ::: "memory");
    __builtin_amdgcn_s_barrier();
  }
  tile_body((nt - 3) & 3, 0, false);
  asm volatile("s_waitcnt vmcnt(4) lgkmcnt(0)" ::: "memory");
  __builtin_amdgcn_s_barrier();
  tile_body((nt - 2) & 3, 0, false);
  asm volatile("s_waitcnt vmcnt(0) lgkmcnt(0)" ::: "memory");
  __builtin_amdgcn_s_barrier();
  tile_body((nt - 1) & 3, 0, false);

  // epilogue: out = (float(half(acc*s_out)) * wscale[n]) * float(half_scale[m])
  const float s_out = mos[0];
  #pragma unroll
  for (int ni = 0; ni < 4; ++ni) {
    const int n_g = bn + (wc << 6) + ni * 16 + lr;
    const float wsc = wscale[n_g];
    #pragma unroll
    for (int mi = 0; mi < 8; ++mi) {
      #pragma unroll
      for (int j = 0; j < 4; ++j) {
        const int m_g = bm + (wr << 7) + mi * 16 + lk * 4 + j;
        const float y = __half2float(__float2half((float)acc[mi][ni][j] * s_out));
        out[(size_t)m_g * N + n_g] = (y * wsc) * __half2float(xs[m_g]);
      }
    }
  }
}

// ---------------------------------------------------------------------------
extern "C" void kernel_launch(void* const* d_in, const int* in_sizes, int n_in,
                              void* d_out, int out_size, void* d_ws, size_t ws_size,
                              hipStream_t stream) {
  const void*  x      = d_in[0];
  const void*  win    = d_in[1];
  const float* wscale = (const float*)d_in[2];
  const float* mos    = (const float*)d_in[3];
  float*       out    = (float*)d_out;

  const int N = in_sizes[2];            // 4096
  const int K = in_sizes[1] / N;        // 4096
  const int M = in_sizes[0] / K;        // 8192

  int8_t* xq = (int8_t*)d_ws + XQ_OFF;
  __half* xs = (__half*)((char*)d_ws + XS_OFF);
  int8_t* w8 = (int8_t*)d_ws + W8_OFF;

  repack_w<<<2048, 256, 0, stream>>>(win, w8, N * K);
  quant_rows<<<M, 256, 0, stream>>>(x, xq, xs, K);

  gemm_w8a8<<<dim3((M >> 8) * (N >> 8)), 512, 0, stream>>>(
      xq, w8, xs, wscale, mos, out, M, N, K);
}